// Round 5
// baseline (349.425 us; speedup 1.0000x reference)
//
#include <hip/hip_runtime.h>
#include <hip/hip_fp16.h>
#include <math.h>

#define U_NUM_ 50000
#define I_NUM_ 50000
#define EMBED_ 64
#define ATT_   64
#define NNZ_   2500000

// ---------------------------------------------------------------------------
// Pass 0: four 50000x64 @ 64x64^T projections, fp32 accumulate, fp16 store,
// written INTERLEAVED so one edge gather serves both the ui and iu halves:
//   utab[row][  0: 64] = Qu = user @ Wq^T + bq   (combo 0)
//   utab[row][ 64:128] = Ku = user @ Wk^T + bk   (combo 3)
//   itab[col][  0: 64] = Ki = item @ Wk^T + bk   (combo 1)
//   itab[col][ 64:128] = Qi = item @ Wq^T + bq   (combo 2)
// 32 rows/block, acc[8]/thread (VGPR-safe; acc[16] spilled in round 1).
// ---------------------------------------------------------------------------
__global__ __launch_bounds__(256) void proj_kernel(
        const float* __restrict__ user_embed, const float* __restrict__ item_embed,
        const float* __restrict__ Wq, const float* __restrict__ bq,
        const float* __restrict__ Wk, const float* __restrict__ bk,
        __half* __restrict__ utab, __half* __restrict__ itab) {
    __shared__ float Wl[ATT_][EMBED_ + 1];
    __shared__ float El[32][EMBED_];
    __shared__ float bl[ATT_];

    const int combo = blockIdx.y;
    const float* E = (combo == 0 || combo == 3) ? user_embed : item_embed;
    const float* W = (combo == 0 || combo == 2) ? Wq : Wk;
    const float* b = (combo == 0 || combo == 2) ? bq : bk;
    __half* tab    = (combo == 0 || combo == 3) ? utab : itab;
    const int off  = (combo == 0 || combo == 1) ? 0 : 64;

    const int tid = threadIdx.x;

    for (int i4 = tid; i4 < 1024; i4 += 256) {
        const int r = i4 >> 4, c4 = (i4 & 15) * 4;
        float4 w = ((const float4*)W)[i4];
        Wl[r][c4 + 0] = w.x; Wl[r][c4 + 1] = w.y;
        Wl[r][c4 + 2] = w.z; Wl[r][c4 + 3] = w.w;
    }
    if (tid < ATT_) bl[tid] = b[tid];

    const int row0 = blockIdx.x * 32;
    for (int i4 = tid; i4 < 512; i4 += 256) {
        const int r = i4 >> 4, c4 = (i4 & 15) * 4;
        const int gr = row0 + r;
        float4 ev = make_float4(0.f, 0.f, 0.f, 0.f);
        if (gr < U_NUM_) ev = ((const float4*)(E + (size_t)gr * EMBED_))[i4 & 15];
        *(float4*)&El[r][c4] = ev;
    }
    __syncthreads();

    const int a  = tid & 63;
    const int rw = tid >> 6;
    float acc[8];
    #pragma unroll
    for (int k = 0; k < 8; ++k) acc[k] = bl[a];

    #pragma unroll 2
    for (int e4 = 0; e4 < 16; ++e4) {
        const float w0 = Wl[a][e4 * 4 + 0];
        const float w1 = Wl[a][e4 * 4 + 1];
        const float w2 = Wl[a][e4 * 4 + 2];
        const float w3 = Wl[a][e4 * 4 + 3];
        #pragma unroll
        for (int k = 0; k < 8; ++k) {
            float4 ev = *(const float4*)&El[rw + 4 * k][e4 * 4];
            acc[k] = fmaf(ev.x, w0, fmaf(ev.y, w1, fmaf(ev.z, w2, fmaf(ev.w, w3, acc[k]))));
        }
    }

    #pragma unroll
    for (int k = 0; k < 8; ++k) {
        const int gr = row0 + rw + 4 * k;
        if (gr < U_NUM_) tab[(size_t)gr * 128 + off + a] = __float2half(acc[k]);
    }
}

// ---------------------------------------------------------------------------
// Pass 1: fused ui+iu edge pass, 4x unrolled (edges j, j+Q, j+2Q, j+3Q with
// Q = NNZ/4) -> 8 in-flight uint4 gathers per thread for MLP. 16 lanes per
// edge: lane l loads 16 B chunk l of utab[row] and itab[col] (256 B each);
// lanes 0-7's partial dot = Qu·Ki (ui edge), lanes 8-15's = Ku·Qi (iu edge);
// one 3-step shfl_xor tree reduces both halves. Fast hw transcendentals
// (__logf/__expf, rel err ~2^-21: negligible vs 2e-2 check threshold).
// Max-subtraction skipped: v analytically bounded (<= ~31), exp fits f32.
// ---------------------------------------------------------------------------
__global__ __launch_bounds__(256) void edge_pass1(
        const int* __restrict__ rows, const int* __restrict__ cols,
        const float* __restrict__ u_ui, const float* __restrict__ u_iu,
        const __half* __restrict__ utab, const __half* __restrict__ itab,
        float* __restrict__ out, float* __restrict__ segsum) {
    const int lane = threadIdx.x & 15;
    const int gid  = (blockIdx.x * blockDim.x + threadIdx.x) >> 4;
    const int ngr  = (gridDim.x * blockDim.x) >> 4;
    const int Q    = NNZ_ / 4;

    const uint4* up = (const uint4*)utab;   // 16 chunks of 16 B per 256 B row
    const uint4* ip = (const uint4*)itab;
    const bool iu = (lane & 8) != 0;
    const float* unoise = iu ? u_iu : u_ui;

    union H8 { uint4 u; __half2 h[4]; };

    for (int j = gid; j < Q; j += ngr) {
        const int j0 = j, j1 = j + Q, j2 = j + 2 * Q, j3 = j + 3 * Q;
        const int r0 = rows[j0], c0 = cols[j0];
        const int r1 = rows[j1], c1 = cols[j1];
        const int r2 = rows[j2], c2 = cols[j2];
        const int r3 = rows[j3], c3 = cols[j3];

        H8 a0, b0, a1, b1, a2, b2, a3, b3;
        a0.u = up[(size_t)r0 * 16 + lane]; b0.u = ip[(size_t)c0 * 16 + lane];
        a1.u = up[(size_t)r1 * 16 + lane]; b1.u = ip[(size_t)c1 * 16 + lane];
        a2.u = up[(size_t)r2 * 16 + lane]; b2.u = ip[(size_t)c2 * 16 + lane];
        a3.u = up[(size_t)r3 * 16 + lane]; b3.u = ip[(size_t)c3 * 16 + lane];

        const float n0 = unoise[j0], n1 = unoise[j1];
        const float n2 = unoise[j2], n3 = unoise[j3];

        float p0 = 0.f, p1 = 0.f, p2 = 0.f, p3 = 0.f;
        #pragma unroll
        for (int m = 0; m < 4; ++m) {
            float2 x, y;
            x = __half22float2(a0.h[m]); y = __half22float2(b0.h[m]);
            p0 = fmaf(x.x, y.x, p0); p0 = fmaf(x.y, y.y, p0);
            x = __half22float2(a1.h[m]); y = __half22float2(b1.h[m]);
            p1 = fmaf(x.x, y.x, p1); p1 = fmaf(x.y, y.y, p1);
            x = __half22float2(a2.h[m]); y = __half22float2(b2.h[m]);
            p2 = fmaf(x.x, y.x, p2); p2 = fmaf(x.y, y.y, p2);
            x = __half22float2(a3.h[m]); y = __half22float2(b3.h[m]);
            p3 = fmaf(x.x, y.x, p3); p3 = fmaf(x.y, y.y, p3);
        }
        p0 += __shfl_xor(p0, 1); p1 += __shfl_xor(p1, 1);
        p2 += __shfl_xor(p2, 1); p3 += __shfl_xor(p3, 1);
        p0 += __shfl_xor(p0, 2); p1 += __shfl_xor(p1, 2);
        p2 += __shfl_xor(p2, 2); p3 += __shfl_xor(p3, 2);
        p0 += __shfl_xor(p0, 4); p1 += __shfl_xor(p1, 4);
        p2 += __shfl_xor(p2, 4); p3 += __shfl_xor(p3, 4);
        // lanes 0-7 hold w_ui; lanes 8-15 hold w_iu (per edge)

        const float e0 = __expf(p0 - __logf(-__logf(n0)));   // TAU = 1
        const float e1 = __expf(p1 - __logf(-__logf(n1)));
        const float e2 = __expf(p2 - __logf(-__logf(n2)));
        const float e3 = __expf(p3 - __logf(-__logf(n3)));

        if (lane == 0) {
            out[j0] = e0; atomicAdd(&segsum[r0], e0);
            out[j1] = e1; atomicAdd(&segsum[r1], e1);
            out[j2] = e2; atomicAdd(&segsum[r2], e2);
            out[j3] = e3; atomicAdd(&segsum[r3], e3);
        } else if (lane == 8) {
            out[NNZ_ + j0] = e0; atomicAdd(&segsum[U_NUM_ + c0], e0);
            out[NNZ_ + j1] = e1; atomicAdd(&segsum[U_NUM_ + c1], e1);
            out[NNZ_ + j2] = e2; atomicAdd(&segsum[U_NUM_ + c2], e2);
            out[NNZ_ + j3] = e3; atomicAdd(&segsum[U_NUM_ + c3], e3);
        }
    }
}

// ---------------------------------------------------------------------------
// Pass 2: normalize by segment sum, 4 edges per thread.
// ---------------------------------------------------------------------------
__global__ __launch_bounds__(256) void edge_pass2(
        const int* __restrict__ rows, const int* __restrict__ cols,
        const float* __restrict__ segsum, float* __restrict__ out) {
    int i = blockIdx.x * blockDim.x + threadIdx.x;
    const int stride = gridDim.x * blockDim.x;
    const int n4 = (2 * NNZ_) / 4;
    for (; i < n4; i += stride) {
        float4 v = ((const float4*)out)[i];
        const int base = i * 4;
        int4 seg;
        if (base < NNZ_) {
            seg = *(const int4*)(rows + base);
        } else {
            seg = *(const int4*)(cols + (base - NNZ_));
            seg.x += U_NUM_; seg.y += U_NUM_; seg.z += U_NUM_; seg.w += U_NUM_;
        }
        v.x /= segsum[seg.x];
        v.y /= segsum[seg.y];
        v.z /= segsum[seg.z];
        v.w /= segsum[seg.w];
        ((float4*)out)[i] = v;
    }
}

extern "C" void kernel_launch(void* const* d_in, const int* in_sizes, int n_in,
                              void* d_out, int out_size, void* d_ws, size_t ws_size,
                              hipStream_t stream) {
    const float* user_embed = (const float*)d_in[0];
    const float* item_embed = (const float*)d_in[1];
    const float* Wq = (const float*)d_in[2];
    const float* bq = (const float*)d_in[3];
    const float* Wk = (const float*)d_in[4];
    const float* bk = (const float*)d_in[5];
    const int*   rows = (const int*)d_in[6];
    const int*   cols = (const int*)d_in[7];
    const float* u_ui = (const float*)d_in[8];
    const float* u_iu = (const float*)d_in[9];
    float* out = (float*)d_out;

    __half* utab  = (__half*)d_ws;                                 // 50000*128 fp16 = 12.8 MB
    __half* itab  = utab + (size_t)U_NUM_ * 128;                   // 12.8 MB
    float* segsum = (float*)(itab + (size_t)I_NUM_ * 128);         // 100000 f32

    hipMemsetAsync(segsum, 0, (U_NUM_ + I_NUM_) * sizeof(float), stream);

    dim3 pgrid((U_NUM_ + 31) / 32, 4);
    proj_kernel<<<pgrid, 256, 0, stream>>>(user_embed, item_embed, Wq, bq, Wk, bk, utab, itab);

    edge_pass1<<<2048, 256, 0, stream>>>(rows, cols, u_ui, u_iu, utab, itab, out, segsum);
    edge_pass2<<<2048, 256, 0, stream>>>(rows, cols, segsum, out);
}